// Round 11
// baseline (269.174 us; speedup 1.0000x reference)
//
#include <hip/hip_runtime.h>
#include <math.h>

#define BB 8
#define CC 64
#define NN 32
#define CONV_TOTAL (BB*CC*NN*NN)   // 524288
#define KM_ELEMS (BB*9*CC*CC)      // 294912
#define NCANON 514                 // canonical frequencies per batch

typedef float v2f __attribute__((ext_vector_type(2)));

// readlane (uniform broadcast; lane index is a uniform value)
#define RL(x, l) __uint_as_float(__builtin_amdgcn_readlane(__float_as_uint(x), (l)))

// Kernel A: km stored TRANSPOSED for logdet: km[b][j][i*64+o]
//   = 0.7*tanh(pre[b,o,i,j]) + (o==i && j==4)
// (pre reads are strided; 1.2 MB, L2-resident, one-shot.)
// Also zeroes the 8 logdet accumulators in d_out.
__global__ __launch_bounds__(256) void build_km(const float* __restrict__ pre,
                                                float* __restrict__ km,
                                                float* __restrict__ logdet_out) {
    int idx = blockIdx.x * 256 + threadIdx.x;
    if (blockIdx.x == 0 && threadIdx.x < BB) logdet_out[threadIdx.x] = 0.f;
    if (idx >= KM_ELEMS) return;
    int b   = idx / (9 * 4096);
    int rem = idx - b * (9 * 4096);
    int j   = rem >> 12;       // tap 0..8
    int e   = rem & 4095;      // TRANSPOSED element: i*64 + o
    int o = e & 63, i = e >> 6;
    float v = 0.7f * tanhf(pre[(b * 4096 + o * 64 + i) * 9 + j]);
    if (o == i && j == 4) v += 1.0f;
    km[idx] = v;
}

// Kernel B: direct circular conv. One block per (b,o); 256 threads; each
// thread owns 4 consecutive pixels in a row. Staging reads from the
// transposed km (strided, L2-resident).
__global__ __launch_bounds__(256) void conv_kernel(const float* __restrict__ x,
                                                   const float* __restrict__ km,
                                                   const float* __restrict__ bias,
                                                   float* __restrict__ out) {
    int b = blockIdx.x >> 6, o = blockIdx.x & 63;
    __shared__ float Kms[9][64];
    __shared__ float xs[1024];
    int t = threadIdx.x;
    for (int s = t; s < 576; s += 256) {
        int j = s >> 6, i = s & 63;
        Kms[j][i] = km[(b * 9 + j) * 4096 + (i << 6) + o];   // transposed read
    }
    float bb = bias[(b << 6) + o];
    float acc0 = bb, acc1 = bb, acc2 = bb, acc3 = bb;
    int u = t >> 3, v0 = (t & 7) << 2;
    const float* xb = x + (size_t)(b << 6) * 1024;
    for (int i = 0; i < 64; ++i) {
        float4 xv4 = *(const float4*)(xb + i * 1024 + (t << 2));
        __syncthreads();                       // previous iter done reading xs
        *(float4*)&xs[t << 2] = xv4;
        __syncthreads();                       // xs (and Kms on iter 0) visible
        #pragma unroll
        for (int dy = 0; dy < 3; ++dy) {
            int row = (u + 1 - dy) & 31;
            const float* xr = &xs[row << 5];
            float xv[6];
            #pragma unroll
            for (int q = 0; q < 6; ++q) xv[q] = xr[(v0 - 1 + q) & 31];
            #pragma unroll
            for (int dx = 0; dx < 3; ++dx) {
                float w = Kms[dy * 3 + dx][i];
                acc0 += w * xv[2 - dx];
                acc1 += w * xv[3 - dx];
                acc2 += w * xv[4 - dx];
                acc3 += w * xv[5 - dx];
            }
        }
    }
    float4 r = make_float4(acc0, acc1, acc2, acc3);
    *(float4*)(out + ((size_t)blockIdx.x << 10) + (u << 5) + v0) = r;
}

// Kernel C: blocked unpivoted LU, panel width 8, COLUMN-MAJOR LDS
// (As[c*64+r]), W-form Schur, panel fact + W computed REDUNDANTLY by all
// 4 waves (pure register work -> no wave0-serial phase), 1 barrier/panel.
__global__ __launch_bounds__(256) void logdet_kernel(const float* __restrict__ km,
                                                     float* __restrict__ logdet_out) {
    int gid = blockIdx.x;
    int b = gid / NCANON, ci = gid - b * NCANON;
    int u, v;
    if (ci < 17)        { u = 0;                  v = ci; }
    else if (ci < 497)  { int r = ci - 17; u = 1 + (r >> 5); v = r & 31; }
    else                { u = 16;                 v = ci - 497; }
    float wgt = ((u == 0 || u == 16) && (v == 0 || v == 16)) ? 1.0f : 2.0f;

    int t = threadIdx.x;
    int wave = t >> 6, lane = t & 63;

    __shared__ v2f As[4096];                         // 32 KB, col-major

    // twiddles w[j] = exp(-2*pi*i*(u*(dy-1)+v*(dx-1))/32) via HW sin/cos
    float wr[9], wi[9];
    #pragma unroll
    for (int j = 0; j < 9; ++j) {
        int dy = j / 3, dx = j % 3;
        float argrev = -(float)(u * (dy - 1) + v * (dx - 1)) * (1.0f / 32.0f);
        argrev = argrev - floorf(argrev);            // [0,1) revolutions
        wr[j] = __builtin_amdgcn_cosf(argrev);
        wi[j] = __builtin_amdgcn_sinf(argrev);
    }

    // Build. km is transposed (e' = c*64 + r), so thread t's float2 load
    // covers rows 2rp,2rp+1 of column c -> coalesced global, contiguous
    // conflict-free LDS float4 write.
    const float* Kb = km + (size_t)b * 36864;
    #pragma unroll
    for (int rep = 0; rep < 8; ++rep) {
        int e2 = t + (rep << 8);                     // pair index: c*32+rp
        float re0 = 0.f, im0 = 0.f, re1 = 0.f, im1 = 0.f;
        #pragma unroll
        for (int j = 0; j < 9; ++j) {
            float2 kv = *(const float2*)(Kb + (j << 12) + (e2 << 1));
            re0 = fmaf(kv.x, wr[j], re0); im0 = fmaf(kv.x, wi[j], im0);
            re1 = fmaf(kv.y, wr[j], re1); im1 = fmaf(kv.y, wi[j], im1);
        }
        *(float4*)&As[e2 << 1] = make_float4(re0, im0, re1, im1);
    }
    __syncthreads();

    float lsum = 0.f;
    int r = lane;
    for (int p = 0; p < 8; ++p) {
        int K0 = p << 3, K7 = K0 | 7;

        // ---- panel fact: ALL waves redundantly; rows = lanes, 8 cols regs
        v2f pc[8];
        #pragma unroll
        for (int j = 0; j < 8; ++j) pc[j] = As[((K0 + j) << 6) | r];
        #pragma unroll
        for (int k = 0; k < 8; ++k) {
            int K = K0 + k;
            float px = RL(pc[k].x, K), py = RL(pc[k].y, K);
            float mag = fmaf(px, px, py * py);
            lsum += 0.5f * __logf(mag);
            float inv = __builtin_amdgcn_rcpf(mag);
            float mr = (pc[k].x * px + pc[k].y * py) * inv;
            float mi = (pc[k].y * px - pc[k].x * py) * inv;
            bool act = r > K;
            mr = act ? mr : 0.f; mi = act ? mi : 0.f;
            pc[k].x = act ? mr : pc[k].x;            // store multiplier (L)
            pc[k].y = act ? mi : pc[k].y;
            #pragma unroll
            for (int j = k + 1; j < 8; ++j) {
                float ux = RL(pc[j].x, K), uy = RL(pc[j].y, K);
                pc[j].x = fmaf(-mr, ux, fmaf( mi, uy, pc[j].x));
                pc[j].y = fmaf(-mr, uy, fmaf(-mi, ux, pc[j].y));
            }
        }

        if (p < 7) {
            // ---- W row per lane via back-substitution: W * L_p = L_trail
            // Lp(q,j) = RL(pc[j], K0+q); garbage rows masked to 0.
            bool act = r > K7;
            v2f W[8];
            #pragma unroll
            for (int j = 7; j >= 0; --j) {
                v2f w = pc[j];
                #pragma unroll
                for (int q = j + 1; q < 8; ++q) {
                    float lx = RL(pc[j].x, K0 + q), ly = RL(pc[j].y, K0 + q);
                    w.x = fmaf(-W[q].x, lx, fmaf( W[q].y, ly, w.x));
                    w.y = fmaf(-W[q].x, ly, fmaf(-W[q].y, lx, w.y));
                }
                W[j].x = act ? w.x : 0.f;
                W[j].y = act ? w.y : 0.f;
            }

            // ---- Schur: A[r][c] -= W(r,:) . A_top(:,c); raw top rows as
            // 4 uniform b128 reads at immediate offsets; cols split by wave.
            for (int c = K0 + 8 + wave; c < 64; c += 4) {
                v2f* col = As + (c << 6);
                v2f a = col[r];
                float4 t01 = *(const float4*)(col + K0);
                float4 t23 = *(const float4*)(col + K0 + 2);
                float4 t45 = *(const float4*)(col + K0 + 4);
                float4 t67 = *(const float4*)(col + K0 + 6);
                a.x = fmaf(-W[0].x, t01.x, fmaf( W[0].y, t01.y, a.x));
                a.y = fmaf(-W[0].x, t01.y, fmaf(-W[0].y, t01.x, a.y));
                a.x = fmaf(-W[1].x, t01.z, fmaf( W[1].y, t01.w, a.x));
                a.y = fmaf(-W[1].x, t01.w, fmaf(-W[1].y, t01.z, a.y));
                a.x = fmaf(-W[2].x, t23.x, fmaf( W[2].y, t23.y, a.x));
                a.y = fmaf(-W[2].x, t23.y, fmaf(-W[2].y, t23.x, a.y));
                a.x = fmaf(-W[3].x, t23.z, fmaf( W[3].y, t23.w, a.x));
                a.y = fmaf(-W[3].x, t23.w, fmaf(-W[3].y, t23.z, a.y));
                a.x = fmaf(-W[4].x, t45.x, fmaf( W[4].y, t45.y, a.x));
                a.y = fmaf(-W[4].x, t45.y, fmaf(-W[4].y, t45.x, a.y));
                a.x = fmaf(-W[5].x, t45.z, fmaf( W[5].y, t45.w, a.x));
                a.y = fmaf(-W[5].x, t45.w, fmaf(-W[5].y, t45.z, a.y));
                a.x = fmaf(-W[6].x, t67.x, fmaf( W[6].y, t67.y, a.x));
                a.y = fmaf(-W[6].x, t67.y, fmaf(-W[6].y, t67.x, a.y));
                a.x = fmaf(-W[7].x, t67.z, fmaf( W[7].y, t67.w, a.x));
                a.y = fmaf(-W[7].x, t67.w, fmaf(-W[7].y, t67.z, a.y));
                if (act) col[r] = a;
            }
        }
        __syncthreads();                             // one barrier per panel
    }
    if (t == 0) atomicAdd(&logdet_out[b], wgt * lsum);
}

extern "C" void kernel_launch(void* const* d_in, const int* in_sizes, int n_in,
                              void* d_out, int out_size, void* d_ws, size_t ws_size,
                              hipStream_t stream) {
    const float* conv_in    = (const float*)d_in[0];
    const float* pre_kernel = (const float*)d_in[1];
    const float* bias       = (const float*)d_in[2];
    float* out = (float*)d_out;
    float* km  = (float*)d_ws;                 // 294912 floats = 1.18 MB
    float* logdet_out = out + CONV_TOTAL;

    build_km<<<KM_ELEMS / 256, 256, 0, stream>>>(pre_kernel, km, logdet_out);
    conv_kernel<<<BB * CC, 256, 0, stream>>>(conv_in, km, bias, out);
    logdet_kernel<<<BB * NCANON, 256, 0, stream>>>(km, logdet_out);
}